// Round 16
// baseline (1011.537 us; speedup 1.0000x reference)
//
#include <hip/hip_runtime.h>
#include <math.h>

#define TT   1024
#define DD   768
#define HH   12
#define LLAY 6
#define DFFN 3072
#define BB   2
#define NTOK (BB*TT)   // 2048

typedef __bf16 bf16;
typedef __attribute__((ext_vector_type(8))) __bf16 bf16x8;
typedef __attribute__((ext_vector_type(4))) __bf16 bf16x4;
typedef __attribute__((ext_vector_type(4))) float f32x4;

__device__ inline unsigned pack_bf16x2(float a, float b) {
    union { bf16 h[2]; unsigned u; } un;
    un.h[0] = (bf16)a; un.h[1] = (bf16)b;
    return un.u;
}

// async global->LDS, 16B per lane; LDS dest is wave-uniform base (+lane*16 by HW)
__device__ inline void gload16(const bf16* g, bf16* l) {
    __builtin_amdgcn_global_load_lds((const void*)g, (void*)l, 16, 0, 0);
}

template<int N> __device__ inline void waitcnt_vm() {
    if constexpr (N == 0) asm volatile("s_waitcnt vmcnt(0)" ::: "memory");
    else if constexpr (N == 3) asm volatile("s_waitcnt vmcnt(3)" ::: "memory");
    else if constexpr (N == 4) asm volatile("s_waitcnt vmcnt(4)" ::: "memory");
}

// ---------------- embedding ----------------
__global__ __launch_bounds__(256) void embed_kernel(const int* __restrict__ idx,
                                                    const float* __restrict__ tok,
                                                    const float* __restrict__ pos,
                                                    float* __restrict__ x) {
    int bt = blockIdx.x;
    int t  = bt % TT;
    int id = idx[bt];
    const float* te = tok + (size_t)id * DD;
    const float* pe = pos + (size_t)t * DD;
    float* xr = x + (size_t)bt * DD;
    for (int d = threadIdx.x; d < DD; d += 256) xr[d] = te[d] + pe[d];
}

// ---------------- layernorm: wave-per-row, f32 in -> bf16 out ----------------
__global__ __launch_bounds__(256) void ln_kernel(const float* __restrict__ in,
                                                 const float* __restrict__ g,
                                                 const float* __restrict__ b,
                                                 bf16* __restrict__ out) {
    const int wid = threadIdx.x >> 6, lane = threadIdx.x & 63;
    const int row = blockIdx.x * 4 + wid;
    const float* xr = in + (size_t)row * DD;
    float4 v[3];
    float s = 0.f, s2 = 0.f;
#pragma unroll
    for (int j = 0; j < 3; ++j) {
        v[j] = *(const float4*)&xr[lane * 4 + 256 * j];
        s  += v[j].x + v[j].y + v[j].z + v[j].w;
        s2 += v[j].x * v[j].x + v[j].y * v[j].y + v[j].z * v[j].z + v[j].w * v[j].w;
    }
    for (int off = 32; off; off >>= 1) { s += __shfl_down(s, off); s2 += __shfl_down(s2, off); }
    s = __shfl(s, 0); s2 = __shfl(s2, 0);
    const float mu = s / (float)DD;
    const float rs = rsqrtf(s2 / (float)DD - mu * mu + 1e-5f);
    bf16* orow = out + (size_t)row * DD;
#pragma unroll
    for (int j = 0; j < 3; ++j) {
        float4 gg = *(const float4*)&g[lane * 4 + 256 * j];
        float4 bb = *(const float4*)&b[lane * 4 + 256 * j];
        bf16x4 o;
        o[0] = (bf16)((v[j].x - mu) * rs * gg.x + bb.x);
        o[1] = (bf16)((v[j].y - mu) * rs * gg.y + bb.y);
        o[2] = (bf16)((v[j].z - mu) * rs * gg.z + bb.z);
        o[3] = (bf16)((v[j].w - mu) * rs * gg.w + bb.w);
        *(bf16x4*)&orow[lane * 4 + 256 * j] = o;
    }
}

// ---------------- 64x64 transpose+convert tile: coalesced 128B bf16 rows ------
__device__ inline void convT_tile64(const float* __restrict__ in, bf16* __restrict__ out,
                                    int K, int N, int k0, int n0) {
    __shared__ float tile[64][65];
    const int c = threadIdx.x & 63, q = threadIdx.x >> 6;   // q 0..3
#pragma unroll
    for (int i = 0; i < 16; ++i)
        tile[q + i * 4][c] = in[(size_t)(k0 + q + i * 4) * N + n0 + c];
    __syncthreads();
#pragma unroll
    for (int i = 0; i < 16; ++i)
        out[(size_t)(n0 + q + i * 4) * K + k0 + c] = (bf16)tile[c][q + i * 4];
}

// single-weight version (LM head): grid (N/64, K/64)
__global__ __launch_bounds__(256) void convT_kernel(const float* __restrict__ in,
                                                    bf16* __restrict__ out,
                                                    int K, int N) {
    convT_tile64(in, out, K, N, blockIdx.y * 64, blockIdx.x * 64);
}

// one layer's 4 weights in one launch (1728 blocks of 64x64 tiles)
__global__ __launch_bounds__(256) void convT4_kernel(const float* __restrict__ w0,
                                                     const float* __restrict__ w1,
                                                     const float* __restrict__ w2,
                                                     const float* __restrict__ w3,
                                                     bf16* __restrict__ o0,
                                                     bf16* __restrict__ o1,
                                                     bf16* __restrict__ o2,
                                                     bf16* __restrict__ o3) {
    int bid = blockIdx.x;
    const float* in; bf16* out; int K, N, t;
    if (bid < 432)       { in = w0; out = o0; K = 768;  N = 2304; t = bid; }          // Wqkv 12x36
    else if (bid < 576)  { in = w1; out = o1; K = 768;  N = 768;  t = bid - 432; }    // Wo   12x12
    else if (bid < 1152) { in = w2; out = o2; K = 768;  N = 3072; t = bid - 576; }    // W1   12x48
    else                 { in = w3; out = o3; K = 3072; N = 768;  t = bid - 1152; }   // W2   48x12
    int nt = N / 64;
    convT_tile64(in, out, K, N, (t / nt) * 64, (t % nt) * 64);
}

// ---------------- bf16 MFMA GEMM (small-N layer GEMMs): 3-deep counted-vmcnt --
// EPI: 2 +bias+res f32 (only variant used now)
template<int BM, int EPI>
__global__ __launch_bounds__(256) void mgemm(const bf16* __restrict__ A,
                                             const bf16* __restrict__ Bt,
                                             const float* __restrict__ bias,
                                             const float* __restrict__ res,
                                             void* __restrict__ Cout,
                                             bf16* __restrict__ vtout,
                                             int M, int N, int K) {
    constexpr int MF = BM / 32;
    constexpr int NF = 4;
    constexpr int AIT = BM / 64;
    constexpr int STG = AIT + 2;          // gloads per wave per stage
    constexpr int ASZ = BM * 32;          // elements
    constexpr int BUFE = ASZ + 128 * 32;  // elements per phase buffer
    __shared__ __align__(16) bf16 smem[3 * BUFE];
    int bm = blockIdx.y * BM;
    int bn = blockIdx.x * 128;
    int tid = threadIdx.x;
    int lane = tid & 63;
    int w = tid >> 6;
    int wr = w >> 1, wc = w & 1;
    int l15 = lane & 15, g = lane >> 4;

    f32x4 acc[MF][NF];
#pragma unroll
    for (int m = 0; m < MF; ++m)
#pragma unroll
        for (int n = 0; n < NF; ++n) acc[m][n] = (f32x4){0.f, 0.f, 0.f, 0.f};

    int r = lane >> 2;
    int koff = ((lane & 3) ^ ((r >> 1) & 3)) * 8;     // pre-swizzled global source
    const bf16* Ab = A + (size_t)(bm + w * 16 + r) * K + koff;
    const bf16* Bb = Bt + (size_t)(bn + w * 16 + r) * K + koff;

    auto stage = [&](int p, int k0) {
        bf16* base = smem + p * BUFE;
        bf16* Asb = base + w * 16 * 32;
        bf16* Bsb = base + ASZ + w * 16 * 32;
#pragma unroll
        for (int it = 0; it < AIT; ++it)
            gload16(Ab + (size_t)(it * 64) * K + k0, Asb + it * 64 * 32);
#pragma unroll
        for (int it = 0; it < 2; ++it)
            gload16(Bb + (size_t)(it * 64) * K + k0, Bsb + it * 64 * 32);
    };

    stage(0, 0);
    stage(1, 32);
    waitcnt_vm<STG>();        // buf0 landed (stage1 still in flight)
    __builtin_amdgcn_s_barrier();
    int cur = 0;

    for (int k0 = 0; k0 < K; k0 += 32) {
        const bf16* Ac = smem + cur * BUFE;
        const bf16* Bc = Ac + ASZ;
        bf16x8 af[MF], bfv[NF];
#pragma unroll
        for (int m = 0; m < MF; ++m) {
            int row = wr * (BM / 2) + m * 16 + l15;
            int gs = g ^ ((row >> 1) & 3);            // read-side swizzle
            af[m] = *(const bf16x8*)&Ac[row * 32 + gs * 8];
        }
#pragma unroll
        for (int n = 0; n < NF; ++n) {
            int row = wc * 64 + n * 16 + l15;
            int gs = g ^ ((row >> 1) & 3);
            bfv[n] = *(const bf16x8*)&Bc[row * 32 + gs * 8];
        }
        bool st = (k0 + 64 < K);
        if (st) {
            int nxt = cur + 2; if (nxt >= 3) nxt -= 3;
            stage(nxt, k0 + 64);                      // lands ~2 K-steps later
        }
#pragma unroll
        for (int m = 0; m < MF; ++m)
#pragma unroll
            for (int n = 0; n < NF; ++n)
                acc[m][n] = __builtin_amdgcn_mfma_f32_16x16x32_bf16(af[m], bfv[n], acc[m][n], 0, 0, 0);
        if (st) waitcnt_vm<STG>();    // prev stage landed; this one stays in flight
        else    waitcnt_vm<0>();
        __builtin_amdgcn_s_barrier();
        cur = (cur == 2) ? 0 : cur + 1;
    }

    int lq = g * 4;
#pragma unroll
    for (int m = 0; m < MF; ++m) {
#pragma unroll
        for (int n = 0; n < NF; ++n) {
            int col = bn + wc * 64 + n * 16 + l15;
            float bv = bias[col];
#pragma unroll
            for (int j = 0; j < 4; ++j) {
                int row = bm + wr * (BM / 2) + m * 16 + lq + j;
                float v = acc[m][n][j] + bv;
                if (EPI == 2) {
                    ((float*)Cout)[(size_t)row * N + col] = v + res[(size_t)row * N + col];
                } else if (EPI == 3) {
                    v = 0.5f * v * (1.f + erff(v * 0.70710678118654752f));
                    ((bf16*)Cout)[(size_t)row * N + col] = (bf16)v;
                } else {
                    ((bf16*)Cout)[(size_t)row * N + col] = (bf16)v;
                }
            }
        }
    }
    (void)vtout;
}

// ---------------- big-tile GEMM: 256x128, 8 waves (4Mx2N), BK=32, 2-buffer ----
// 48KB LDS -> 3 blocks/CU (cross-block overlap hides end-of-step drains).
// Chunk swizzle: 16B chunk c of 64B row r at c ^ ((r>>1)&3), both sides.
template<int EPI>
__global__ __launch_bounds__(512, 2) void bgemm(const bf16* __restrict__ A,
                                                const bf16* __restrict__ Bt,
                                                const float* __restrict__ bias,
                                                void* __restrict__ Cout,
                                                bf16* __restrict__ vtout,
                                                int N, int K) {
    constexpr int ABUF = 256 * 32;           // A elems/buffer (16KB)
    constexpr int BUFE = ABUF + 128 * 32;    // +B (8KB) = 24KB
    __shared__ __align__(16) bf16 smem[2 * BUFE];   // 48 KiB
    const int bm = blockIdx.y * 256;
    const int bn = blockIdx.x * 128;
    const int tid = threadIdx.x;
    const int w = tid >> 6, lane = tid & 63;
    const int wm = w >> 1, wn = w & 1;       // 4M x 2N wave grid
    const int l15 = lane & 15, g = lane >> 4;

    const int fcol = (g ^ ((l15 >> 1) & 3)) * 8;    // read-side swizzled chunk

    const int rA = lane >> 2;
    const int csw = ((lane & 3) ^ ((lane >> 3) & 3)) * 8;   // inverse-swizzled src col
    const bf16* a0 = A  + (size_t)(bm + w * 16 + rA) * K + csw;
    const bf16* b0 = Bt + (size_t)(bn + w * 16 + rA) * K + csw;
    const int ld0 = (w * 16) * 32;
    const int ld1 = (w * 16 + 128) * 32;

    f32x4 acc[4][4];
#pragma unroll
    for (int m = 0; m < 4; ++m)
#pragma unroll
        for (int n = 0; n < 4; ++n) acc[m][n] = (f32x4){0.f, 0.f, 0.f, 0.f};

    auto stagef = [&](int p, int kelem) {
        bf16* base = smem + p * BUFE;
        gload16(a0 + kelem, base + ld0);
        gload16(a0 + (size_t)128 * K + kelem, base + ld1);
        gload16(b0 + kelem, base + ABUF + ld0);   // B rows 0..127 (tid>>2)
    };

    stagef(0, 0);
    __syncthreads();
    int cur = 0;

    const int NT = K / 32;
    for (int t = 0; t < NT; ++t) {
        if (t + 1 < NT) stagef(cur ^ 1, (t + 1) * 32);   // issued early
        const bf16* Ar = smem + cur * BUFE;
        const bf16* Br = Ar + ABUF;
        bf16x8 af[4], bfv[4];
#pragma unroll
        for (int m = 0; m < 4; ++m)
            af[m] = *(const bf16x8*)&Ar[(wm * 64 + m * 16 + l15) * 32 + fcol];
#pragma unroll
        for (int n = 0; n < 4; ++n)
            bfv[n] = *(const bf16x8*)&Br[(wn * 64 + n * 16 + l15) * 32 + fcol];
        __builtin_amdgcn_s_setprio(1);
#pragma unroll
        for (int m = 0; m < 4; ++m)
#pragma unroll
            for (int n = 0; n < 4; ++n)
                acc[m][n] = __builtin_amdgcn_mfma_f32_16x16x32_bf16(af[m], bfv[n], acc[m][n], 0, 0, 0);
        __builtin_amdgcn_s_setprio(0);
        __syncthreads();            // drains vmcnt(0): next buffer published
        cur ^= 1;
    }

    const int lq = g * 4;
#pragma unroll
    for (int m = 0; m < 4; ++m) {
#pragma unroll
        for (int n = 0; n < 4; ++n) {
            int col = bn + wn * 64 + n * 16 + l15;
            float bv = bias[col];
            if (EPI == 4 && col >= 2 * DD) {
                int row0 = bm + wm * 64 + m * 16 + lq;
                int b = row0 >> 10, t0 = row0 & 1023;
                int hd = col - 2 * DD;
                union { bf16 h[4]; unsigned long long u; } pk;
#pragma unroll
                for (int j = 0; j < 4; ++j) pk.h[j] = (bf16)(acc[m][n][j] + bv);
                *(unsigned long long*)&vtout[((size_t)(b * DD + hd)) * TT + t0] = pk.u;
            } else {
#pragma unroll
                for (int j = 0; j < 4; ++j) {
                    int row = bm + wm * 64 + m * 16 + lq + j;
                    float v = acc[m][n][j] + bv;
                    if (EPI == 3) {
                        v = 0.5f * v * (1.f + erff(v * 0.70710678118654752f));
                        ((bf16*)Cout)[(size_t)row * N + col] = (bf16)v;
                    } else { // EPI == 4 Q/K columns
                        if (col < DD) v *= 0.125f;
                        ((bf16*)Cout)[(size_t)row * N + col] = (bf16)v;
                    }
                }
            }
        }
    }
}

// ---------------- LM head GEMM: 256x256, 8 waves, BK=32, 2-buffer (64KB) ------
// 2 blocks/CU: cross-block wave overlap hides the per-step drain.
// XCD swizzle (r11): FETCH 198->73MB. Chunk swizzle as bgemm.
__global__ __launch_bounds__(512, 2) void lmgemm(const bf16* __restrict__ A,
                                                 const bf16* __restrict__ Bt,
                                                 float* __restrict__ C) {
    constexpr int ABUF = 256 * 32;           // 16KB
    constexpr int BUFE = 2 * ABUF;           // A+B = 32KB
    __shared__ __align__(16) bf16 smem[2 * BUFE];   // 64 KiB
    const int orig = blockIdx.x;             // 0..1023
    const int xcd = orig & 7, local = orig >> 3;
    const int bnb = xcd * 16 + (local >> 3);
    if (bnb >= 125) return;
    const int bm = (local & 7) * 256;
    const int bn = bnb * 256;
    const int tid = threadIdx.x;
    const int w = tid >> 6, lane = tid & 63;
    const int wm = w >> 2, wn = w & 3;
    const int l15 = lane & 15, g = lane >> 4;

    const int fcol = (g ^ ((l15 >> 1) & 3)) * 8;

    const int rA = lane >> 2;
    const int csw = ((lane & 3) ^ ((lane >> 3) & 3)) * 8;
    const bf16* a0 = A  + (size_t)(bm + w * 16 + rA) * DD + csw;
    const bf16* b0 = Bt + (size_t)(bn + w * 16 + rA) * DD + csw;
    const int ld0 = (w * 16) * 32;
    const int ld1 = (w * 16 + 128) * 32;

    f32x4 acc[8][4];
#pragma unroll
    for (int m = 0; m < 8; ++m)
#pragma unroll
        for (int n = 0; n < 4; ++n) acc[m][n] = (f32x4){0.f, 0.f, 0.f, 0.f};

    auto stagef = [&](int p, int kelem) {
        bf16* base = smem + p * BUFE;
        gload16(a0 + kelem, base + ld0);
        gload16(a0 + (size_t)128 * DD + kelem, base + ld1);
        gload16(b0 + kelem, base + ABUF + ld0);
        gload16(b0 + (size_t)128 * DD + kelem, base + ABUF + ld1);
    };

    stagef(0, 0);
    __syncthreads();
    int cur = 0;

    for (int t = 0; t < 24; ++t) {
        if (t < 23) stagef(cur ^ 1, (t + 1) * 32);   // issued early
        const bf16* Ar = smem + cur * BUFE;
        const bf16* Br = Ar + ABUF;
        bf16x8 af[8], bfv[4];
#pragma unroll
        for (int m = 0; m < 8; ++m)
            af[m] = *(const bf16x8*)&Ar[(wm * 128 + m * 16 + l15) * 32 + fcol];
#pragma unroll
        for (int n = 0; n < 4; ++n)
            bfv[n] = *(const bf16x8*)&Br[(wn * 64 + n * 16 + l15) * 32 + fcol];
        __builtin_amdgcn_s_setprio(1);
#pragma unroll
        for (int m = 0; m < 8; ++m)
#pragma unroll
            for (int n = 0; n < 4; ++n)
                acc[m][n] = __builtin_amdgcn_mfma_f32_16x16x32_bf16(af[m], bfv[n], acc[m][n], 0, 0, 0);
        __builtin_amdgcn_s_setprio(0);
        __syncthreads();            // drains vmcnt(0): next buffer published
        cur ^= 1;
    }

    // epilogue: per-wave disjoint LDS transpose, barrier-free, cached stores
    float* eb = (float*)smem + w * (16 * 68);       // 34.8KB < 64KB
    const int rr = lane >> 2, c0 = (lane & 3) * 16;
#pragma unroll
    for (int mf = 0; mf < 8; ++mf) {
#pragma unroll
        for (int n = 0; n < 4; ++n)
#pragma unroll
            for (int j = 0; j < 4; ++j)
                eb[(g * 4 + j) * 68 + n * 16 + l15] = acc[mf][n][j];
        asm volatile("s_waitcnt lgkmcnt(0)" ::: "memory");   // writes visible in-wave
        const float* src = &eb[rr * 68 + c0];
        float* dst = C + (size_t)(bm + wm * 128 + mf * 16 + rr) * 32000 + bn + wn * 64 + c0;
        *(float4*)(dst + 0)  = *(const float4*)(src + 0);
        *(float4*)(dst + 4)  = *(const float4*)(src + 4);
        *(float4*)(dst + 8)  = *(const float4*)(src + 8);
        *(float4*)(dst + 12) = *(const float4*)(src + 12);
    }
}

// ---------------- MFMA flash attention (T14 async-stage: reg-preload next chunk) --
__global__ __launch_bounds__(256) void fattn_kernel(const bf16* __restrict__ qkv,
                                                    const bf16* __restrict__ vt,
                                                    bf16* __restrict__ o) {
    const int bh = blockIdx.y;
    const int b = bh / HH, h = bh % HH;
    const int qc = gridDim.x - 1 - blockIdx.x;   // longest blocks dispatch first
    const int q0 = qc * 64;
    const int tid = threadIdx.x;
    const int w = tid >> 6, lane = tid & 63;
    const int l15 = lane & 15, g = lane >> 4;

    __shared__ __align__(16) bf16 Ks[64 * 64];
    __shared__ __align__(16) bf16 Vs[64 * 64];
    __shared__ __align__(16) bf16 Ps[4][16 * 64];

    const size_t basebt = (size_t)b * TT;
    const int qw = q0 + w * 16;
    const int qg = qw + l15;

    bf16x8 bq0, bq1;
    {
        const bf16* qp = qkv + (basebt + qw + l15) * 2304 + h * 64 + g * 8;
        bq0 = *(const bf16x8*)(qp);
        bq1 = *(const bf16x8*)(qp + 32);
    }

    float mstate = -1e30f, lstate = 0.f;
    f32x4 oacc[4];
#pragma unroll
    for (int nf = 0; nf < 4; ++nf) oacc[nf] = (f32x4){0.f, 0.f, 0.f, 0.f};

    const int swzA = (l15 & 7) << 4;
    char* const psBase = (char*)&Ps[w][0];

    // staging coords + prologue: chunk 0 into regs
    const int r0 = tid >> 3;
    const int e0 = (tid & 7) * 8;
    bf16x8 kreg[2], vreg[2];
#pragma unroll
    for (int i = 0; i < 2; ++i) {
        int r = r0 + 32 * i;
        kreg[i] = *(const bf16x8*)&qkv[(basebt + r) * 2304 + DD + h * 64 + e0];
        vreg[i] = *(const bf16x8*)&vt[((size_t)bh * 64 + r) * TT + e0];
    }

    const int nchunk = qc + 1;
    for (int c = 0; c < nchunk; ++c) {
        const int kc = c * 64;
        // publish staged regs to LDS (previous readers finished at bottom barrier)
#pragma unroll
        for (int i = 0; i < 2; ++i) {
            int r = r0 + 32 * i;
            int swzW = (r & 7) << 4;
            *(bf16x8*)((char*)Ks + r * 128 + ((e0 * 2) ^ swzW)) = kreg[i];
            *(bf16x8*)((char*)Vs + r * 128 + ((e0 * 2) ^ swzW)) = vreg[i];
        }
        __syncthreads();
        // T14: issue next chunk's loads now; latency hides under compute below
        if (c + 1 < nchunk) {
            const int kc2 = kc + 64;
#pragma unroll
            for (int i = 0; i < 2; ++i) {
                int r = r0 + 32 * i;
                kreg[i] = *(const bf16x8*)&qkv[(basebt + kc2 + r) * 2304 + DD + h * 64 + e0];
                vreg[i] = *(const bf16x8*)&vt[((size_t)bh * 64 + r) * TT + kc2 + e0];
            }
        }
        if (kc <= qw + 15) {
            f32x4 s[4];
            __builtin_amdgcn_s_setprio(1);
#pragma unroll
            for (int mf = 0; mf < 4; ++mf) {
                char* kr = (char*)Ks + (16 * mf + l15) * 128;
                bf16x8 ka0 = *(const bf16x8*)(kr + ((16 * g) ^ swzA));
                bf16x8 ka1 = *(const bf16x8*)(kr + ((64 + 16 * g) ^ swzA));
                f32x4 a = (f32x4){0.f, 0.f, 0.f, 0.f};
                a = __builtin_amdgcn_mfma_f32_16x16x32_bf16(ka0, bq0, a, 0, 0, 0);
                a = __builtin_amdgcn_mfma_f32_16x16x32_bf16(ka1, bq1, a, 0, 0, 0);
                s[mf] = a;
            }
            __builtin_amdgcn_s_setprio(0);
            if (kc + 63 > qw) {
#pragma unroll
                for (int mf = 0; mf < 4; ++mf)
#pragma unroll
                    for (int j = 0; j < 4; ++j)
                        if (kc + 16 * mf + 4 * g + j > qg) s[mf][j] = -1e30f;
            }
            float cm = -1e30f;
#pragma unroll
            for (int mf = 0; mf < 4; ++mf)
#pragma unroll
                for (int j = 0; j < 4; ++j) cm = fmaxf(cm, s[mf][j]);
            cm = fmaxf(cm, __shfl_xor(cm, 16));
            cm = fmaxf(cm, __shfl_xor(cm, 32));
            float mnew = fmaxf(mstate, cm);
            float sc = __expf(mstate - mnew);
            mstate = mnew;
            float p[4][4];
            float psum = 0.f;
#pragma unroll
            for (int mf = 0; mf < 4; ++mf)
#pragma unroll
                for (int j = 0; j < 4; ++j) { float pv = __expf(s[mf][j] - mnew); p[mf][j] = pv; psum += pv; }
            psum += __shfl_xor(psum, 16);
            psum += __shfl_xor(psum, 32);
            lstate = lstate * sc + psum;
#pragma unroll
            for (int mf = 0; mf < 4; ++mf) {
                unsigned lo = pack_bf16x2(p[mf][0], p[mf][1]);
                unsigned hi = pack_bf16x2(p[mf][2], p[mf][3]);
                char* dst = psBase + l15 * 128 + ((32 * mf + 8 * g) ^ swzA);
                *(unsigned*)dst = lo;
                *(unsigned*)(dst + 4) = hi;
            }
            float s0 = __shfl(sc, 4 * g + 0), s1 = __shfl(sc, 4 * g + 1);
            float s2 = __shfl(sc, 4 * g + 2), s3 = __shfl(sc, 4 * g + 3);
#pragma unroll
            for (int nf = 0; nf < 4; ++nf) {
                oacc[nf][0] *= s0; oacc[nf][1] *= s1; oacc[nf][2] *= s2; oacc[nf][3] *= s3;
            }
            bf16x8 pa0 = *(const bf16x8*)(psBase + l15 * 128 + ((16 * g) ^ swzA));
            bf16x8 pa1 = *(const bf16x8*)(psBase + l15 * 128 + ((64 + 16 * g) ^ swzA));
            __builtin_amdgcn_s_setprio(1);
#pragma unroll
            for (int nf = 0; nf < 4; ++nf) {
                char* vr = (char*)Vs + (16 * nf + l15) * 128;
                bf16x8 vb0 = *(const bf16x8*)(vr + ((16 * g) ^ swzA));
                bf16x8 vb1 = *(const bf16x8*)(vr + ((64 + 16 * g) ^ swzA));
                oacc[nf] = __builtin_amdgcn_mfma_f32_16x16x32_bf16(pa0, vb0, oacc[nf], 0, 0, 0);
                oacc[nf] = __builtin_amdgcn_mfma_f32_16x16x32_bf16(pa1, vb1, oacc[nf], 0, 0, 0);
            }
            __builtin_amdgcn_s_setprio(0);
        }
        __syncthreads();   // all reads of LDS[c] done before next publish
    }
    float linv = 1.f / lstate;
    float l0 = __shfl(linv, 4 * g + 0), l1 = __shfl(linv, 4 * g + 1);
    float l2 = __shfl(linv, 4 * g + 2), l3 = __shfl(linv, 4 * g + 3);
    float lj[4] = {l0, l1, l2, l3};
#pragma unroll
    for (int j = 0; j < 4; ++j) {
        bf16* orow = o + (size_t)(basebt + qw + 4 * g + j) * DD + h * 64 + l15;
#pragma unroll
        for (int nf = 0; nf < 4; ++nf)
            orow[16 * nf] = (bf16)(oacc[nf][j] * lj[j]);
    }
}

// ---------------- launcher ----------------
extern "C" void kernel_launch(void* const* d_in, const int* in_sizes, int n_in,
                              void* d_out, int out_size, void* d_ws, size_t ws_size,
                              hipStream_t stream) {
    (void)in_sizes; (void)n_in; (void)out_size; (void)ws_size;
    const int*   idx  = (const int*)d_in[0];
    const float* tok  = (const float*)d_in[1];
    const float* pos  = (const float*)d_in[2];
    const float* Wqkv = (const float*)d_in[3];
    const float* bqkv = (const float*)d_in[4];
    const float* Wo   = (const float*)d_in[5];
    const float* bo   = (const float*)d_in[6];
    const float* ln1g = (const float*)d_in[7];
    const float* ln1b = (const float*)d_in[8];
    const float* ln2g = (const float*)d_in[9];
    const float* ln2b = (const float*)d_in[10];
    const float* W1   = (const float*)d_in[11];
    const float* b1   = (const float*)d_in[12];
    const float* W2   = (const float*)d_in[13];
    const float* b2   = (const float*)d_in[14];
    const float* lnfg = (const float*)d_in[15];
    const float* lnfb = (const float*)d_in[16];
    const float* Wlm  = (const float*)d_in[17];
    float* out = (float*)d_out;

    char* ws = (char*)d_ws;
    float* x     = (float*)(ws);                       // 6,291,456
    bf16*  abuf0 = (bf16*)(ws + 6291456);              // 3,145,728
    bf16*  abuf1 = (bf16*)(ws + 9437184);              // 12,582,912
    bf16*  qkvb  = (bf16*)(ws + 22020096);             // 9,437,184
    bf16*  vtb   = (bf16*)(ws + 31457280);             // 3,145,728
    bf16*  wbuf  = (bf16*)(ws + 34603008);             // 49,152,000

    bf16* wq = wbuf;              // 2304x768
    bf16* wo = wbuf + 1769472;    // 768x768
    bf16* w1 = wbuf + 2359296;    // 3072x768
    bf16* w2 = wbuf + 4718592;    // 768x3072

    embed_kernel<<<NTOK, 256, 0, stream>>>(idx, tok, pos, x);

    for (int l = 0; l < LLAY; ++l) {
        convT4_kernel<<<1728, 256, 0, stream>>>(
            Wqkv + (size_t)l * DD * 3 * DD, Wo + (size_t)l * DD * DD,
            W1 + (size_t)l * DD * DFFN, W2 + (size_t)l * DFFN * DD,
            wq, wo, w1, w2);
        ln_kernel<<<NTOK / 4, 256, 0, stream>>>(x, ln1g + l * DD, ln1b + l * DD, abuf0);
        bgemm<4><<<dim3(3 * DD / 128, NTOK / 256), 512, 0, stream>>>(
            abuf0, wq, bqkv + (size_t)l * 3 * DD, qkvb, vtb, 3 * DD, DD);
        fattn_kernel<<<dim3(TT / 64, BB * HH), 256, 0, stream>>>(qkvb, vtb, abuf0);
        mgemm<64, 2><<<dim3(DD / 128, NTOK / 64), 256, 0, stream>>>(
            abuf0, wo, bo + (size_t)l * DD, x, x, nullptr, NTOK, DD, DD);
        ln_kernel<<<NTOK / 4, 256, 0, stream>>>(x, ln2g + l * DD, ln2b + l * DD, abuf0);
        bgemm<3><<<dim3(DFFN / 128, NTOK / 256), 512, 0, stream>>>(
            abuf0, w1, b1 + (size_t)l * DFFN, abuf1, nullptr, DFFN, DD);
        mgemm<64, 2><<<dim3(DD / 128, NTOK / 64), 256, 0, stream>>>(
            abuf1, w2, b2 + (size_t)l * DD, x, x, nullptr, NTOK, DD, DFFN);
    }
    ln_kernel<<<NTOK / 4, 256, 0, stream>>>(x, lnfg, lnfb, abuf0);
    convT_kernel<<<dim3(32000 / 64, DD / 64), 256, 0, stream>>>(Wlm, wbuf, DD, 32000);
    lmgemm<<<1024, 512, 0, stream>>>(abuf0, wbuf, out);
}

// Round 17
// 963.226 us; speedup vs baseline: 1.0502x; 1.0502x over previous
//
#include <hip/hip_runtime.h>
#include <math.h>

#define TT   1024
#define DD   768
#define HH   12
#define LLAY 6
#define DFFN 3072
#define BB   2
#define NTOK (BB*TT)   // 2048

typedef __bf16 bf16;
typedef __attribute__((ext_vector_type(8))) __bf16 bf16x8;
typedef __attribute__((ext_vector_type(4))) __bf16 bf16x4;
typedef __attribute__((ext_vector_type(4))) float f32x4;

__device__ inline unsigned pack_bf16x2(float a, float b) {
    union { bf16 h[2]; unsigned u; } un;
    un.h[0] = (bf16)a; un.h[1] = (bf16)b;
    return un.u;
}

// async global->LDS, 16B per lane; LDS dest is wave-uniform base (+lane*16 by HW)
__device__ inline void gload16(const bf16* g, bf16* l) {
    __builtin_amdgcn_global_load_lds((const void*)g, (void*)l, 16, 0, 0);
}

template<int N> __device__ inline void waitcnt_vm() {
    if constexpr (N == 0) asm volatile("s_waitcnt vmcnt(0)" ::: "memory");
    else if constexpr (N == 3) asm volatile("s_waitcnt vmcnt(3)" ::: "memory");
    else if constexpr (N == 4) asm volatile("s_waitcnt vmcnt(4)" ::: "memory");
}

// ---------------- embedding ----------------
__global__ __launch_bounds__(256) void embed_kernel(const int* __restrict__ idx,
                                                    const float* __restrict__ tok,
                                                    const float* __restrict__ pos,
                                                    float* __restrict__ x) {
    int bt = blockIdx.x;
    int t  = bt % TT;
    int id = idx[bt];
    const float* te = tok + (size_t)id * DD;
    const float* pe = pos + (size_t)t * DD;
    float* xr = x + (size_t)bt * DD;
    for (int d = threadIdx.x; d < DD; d += 256) xr[d] = te[d] + pe[d];
}

// ---------------- layernorm: wave-per-row, f32 in -> bf16 out ----------------
__global__ __launch_bounds__(256) void ln_kernel(const float* __restrict__ in,
                                                 const float* __restrict__ g,
                                                 const float* __restrict__ b,
                                                 bf16* __restrict__ out) {
    const int wid = threadIdx.x >> 6, lane = threadIdx.x & 63;
    const int row = blockIdx.x * 4 + wid;
    const float* xr = in + (size_t)row * DD;
    float4 v[3];
    float s = 0.f, s2 = 0.f;
#pragma unroll
    for (int j = 0; j < 3; ++j) {
        v[j] = *(const float4*)&xr[lane * 4 + 256 * j];
        s  += v[j].x + v[j].y + v[j].z + v[j].w;
        s2 += v[j].x * v[j].x + v[j].y * v[j].y + v[j].z * v[j].z + v[j].w * v[j].w;
    }
    for (int off = 32; off; off >>= 1) { s += __shfl_down(s, off); s2 += __shfl_down(s2, off); }
    s = __shfl(s, 0); s2 = __shfl(s2, 0);
    const float mu = s / (float)DD;
    const float rs = rsqrtf(s2 / (float)DD - mu * mu + 1e-5f);
    bf16* orow = out + (size_t)row * DD;
#pragma unroll
    for (int j = 0; j < 3; ++j) {
        float4 gg = *(const float4*)&g[lane * 4 + 256 * j];
        float4 bb = *(const float4*)&b[lane * 4 + 256 * j];
        bf16x4 o;
        o[0] = (bf16)((v[j].x - mu) * rs * gg.x + bb.x);
        o[1] = (bf16)((v[j].y - mu) * rs * gg.y + bb.y);
        o[2] = (bf16)((v[j].z - mu) * rs * gg.z + bb.z);
        o[3] = (bf16)((v[j].w - mu) * rs * gg.w + bb.w);
        *(bf16x4*)&orow[lane * 4 + 256 * j] = o;
    }
}

// ---------------- 64x64 transpose+convert tile: coalesced 128B bf16 rows ------
__device__ inline void convT_tile64(const float* __restrict__ in, bf16* __restrict__ out,
                                    int K, int N, int k0, int n0) {
    __shared__ float tile[64][65];
    const int c = threadIdx.x & 63, q = threadIdx.x >> 6;   // q 0..3
#pragma unroll
    for (int i = 0; i < 16; ++i)
        tile[q + i * 4][c] = in[(size_t)(k0 + q + i * 4) * N + n0 + c];
    __syncthreads();
#pragma unroll
    for (int i = 0; i < 16; ++i)
        out[(size_t)(n0 + q + i * 4) * K + k0 + c] = (bf16)tile[c][q + i * 4];
}

// single-weight version (LM head): grid (N/64, K/64)
__global__ __launch_bounds__(256) void convT_kernel(const float* __restrict__ in,
                                                    bf16* __restrict__ out,
                                                    int K, int N) {
    convT_tile64(in, out, K, N, blockIdx.y * 64, blockIdx.x * 64);
}

// one layer's 4 weights in one launch (1728 blocks of 64x64 tiles)
__global__ __launch_bounds__(256) void convT4_kernel(const float* __restrict__ w0,
                                                     const float* __restrict__ w1,
                                                     const float* __restrict__ w2,
                                                     const float* __restrict__ w3,
                                                     bf16* __restrict__ o0,
                                                     bf16* __restrict__ o1,
                                                     bf16* __restrict__ o2,
                                                     bf16* __restrict__ o3) {
    int bid = blockIdx.x;
    const float* in; bf16* out; int K, N, t;
    if (bid < 432)       { in = w0; out = o0; K = 768;  N = 2304; t = bid; }          // Wqkv 12x36
    else if (bid < 576)  { in = w1; out = o1; K = 768;  N = 768;  t = bid - 432; }    // Wo   12x12
    else if (bid < 1152) { in = w2; out = o2; K = 768;  N = 3072; t = bid - 576; }    // W1   12x48
    else                 { in = w3; out = o3; K = 3072; N = 768;  t = bid - 1152; }   // W2   48x12
    int nt = N / 64;
    convT_tile64(in, out, K, N, (t / nt) * 64, (t % nt) * 64);
}

// ---------------- bf16 MFMA GEMM (small-N layer GEMMs): 3-deep counted-vmcnt --
// EPI: 2 +bias+res f32
template<int BM, int EPI>
__global__ __launch_bounds__(256) void mgemm(const bf16* __restrict__ A,
                                             const bf16* __restrict__ Bt,
                                             const float* __restrict__ bias,
                                             const float* __restrict__ res,
                                             void* __restrict__ Cout,
                                             bf16* __restrict__ vtout,
                                             int M, int N, int K) {
    constexpr int MF = BM / 32;
    constexpr int NF = 4;
    constexpr int AIT = BM / 64;
    constexpr int STG = AIT + 2;          // gloads per wave per stage
    constexpr int ASZ = BM * 32;          // elements
    constexpr int BUFE = ASZ + 128 * 32;  // elements per phase buffer
    __shared__ __align__(16) bf16 smem[3 * BUFE];
    int bm = blockIdx.y * BM;
    int bn = blockIdx.x * 128;
    int tid = threadIdx.x;
    int lane = tid & 63;
    int w = tid >> 6;
    int wr = w >> 1, wc = w & 1;
    int l15 = lane & 15, g = lane >> 4;

    f32x4 acc[MF][NF];
#pragma unroll
    for (int m = 0; m < MF; ++m)
#pragma unroll
        for (int n = 0; n < NF; ++n) acc[m][n] = (f32x4){0.f, 0.f, 0.f, 0.f};

    int r = lane >> 2;
    int koff = ((lane & 3) ^ ((r >> 1) & 3)) * 8;     // pre-swizzled global source
    const bf16* Ab = A + (size_t)(bm + w * 16 + r) * K + koff;
    const bf16* Bb = Bt + (size_t)(bn + w * 16 + r) * K + koff;

    auto stage = [&](int p, int k0) {
        bf16* base = smem + p * BUFE;
        bf16* Asb = base + w * 16 * 32;
        bf16* Bsb = base + ASZ + w * 16 * 32;
#pragma unroll
        for (int it = 0; it < AIT; ++it)
            gload16(Ab + (size_t)(it * 64) * K + k0, Asb + it * 64 * 32);
#pragma unroll
        for (int it = 0; it < 2; ++it)
            gload16(Bb + (size_t)(it * 64) * K + k0, Bsb + it * 64 * 32);
    };

    stage(0, 0);
    stage(1, 32);
    waitcnt_vm<STG>();        // buf0 landed (stage1 still in flight)
    __builtin_amdgcn_s_barrier();
    int cur = 0;

    for (int k0 = 0; k0 < K; k0 += 32) {
        const bf16* Ac = smem + cur * BUFE;
        const bf16* Bc = Ac + ASZ;
        bf16x8 af[MF], bfv[NF];
#pragma unroll
        for (int m = 0; m < MF; ++m) {
            int row = wr * (BM / 2) + m * 16 + l15;
            int gs = g ^ ((row >> 1) & 3);            // read-side swizzle
            af[m] = *(const bf16x8*)&Ac[row * 32 + gs * 8];
        }
#pragma unroll
        for (int n = 0; n < NF; ++n) {
            int row = wc * 64 + n * 16 + l15;
            int gs = g ^ ((row >> 1) & 3);
            bfv[n] = *(const bf16x8*)&Bc[row * 32 + gs * 8];
        }
        bool st = (k0 + 64 < K);
        if (st) {
            int nxt = cur + 2; if (nxt >= 3) nxt -= 3;
            stage(nxt, k0 + 64);                      // lands ~2 K-steps later
        }
#pragma unroll
        for (int m = 0; m < MF; ++m)
#pragma unroll
            for (int n = 0; n < NF; ++n)
                acc[m][n] = __builtin_amdgcn_mfma_f32_16x16x32_bf16(af[m], bfv[n], acc[m][n], 0, 0, 0);
        if (st) waitcnt_vm<STG>();    // prev stage landed; this one stays in flight
        else    waitcnt_vm<0>();
        __builtin_amdgcn_s_barrier();
        cur = (cur == 2) ? 0 : cur + 1;
    }

    int lq = g * 4;
#pragma unroll
    for (int m = 0; m < MF; ++m) {
#pragma unroll
        for (int n = 0; n < NF; ++n) {
            int col = bn + wc * 64 + n * 16 + l15;
            float bv = bias[col];
#pragma unroll
            for (int j = 0; j < 4; ++j) {
                int row = bm + wr * (BM / 2) + m * 16 + lq + j;
                float v = acc[m][n][j] + bv;
                if (EPI == 2) {
                    ((float*)Cout)[(size_t)row * N + col] = v + res[(size_t)row * N + col];
                } else if (EPI == 3) {
                    v = 0.5f * v * (1.f + erff(v * 0.70710678118654752f));
                    ((bf16*)Cout)[(size_t)row * N + col] = (bf16)v;
                } else {
                    ((bf16*)Cout)[(size_t)row * N + col] = (bf16)v;
                }
            }
        }
    }
    (void)vtout;
}

// ---------------- big-tile GEMM: 256x128, 8 waves (4Mx2N), BK=64, r8 schedule --
// For qkv (EPI=4) and ffn1 (EPI=3): lmgemm skeleton, wave tile 64x64, acc[4][4].
// Chunk swizzle: 16B chunk c of 128B row r at c ^ ((r>>1)&7), both sides.
template<int EPI>
__global__ __launch_bounds__(512, 2) void bgemm(const bf16* __restrict__ A,
                                                const bf16* __restrict__ Bt,
                                                const float* __restrict__ bias,
                                                void* __restrict__ Cout,
                                                bf16* __restrict__ vtout,
                                                int N, int K) {
    constexpr int ABUF = 256 * 64;           // A elems/buffer (32KB)
    constexpr int BUFE = ABUF + 128 * 64;    // +B (16KB) = 48KB
    __shared__ __align__(16) bf16 smem[2 * BUFE];   // 96 KiB
    const int bm = blockIdx.y * 256;
    const int bn = blockIdx.x * 128;
    const int tid = threadIdx.x;
    const int w = tid >> 6, lane = tid & 63;
    const int wm = w >> 1, wn = w & 1;       // 4M x 2N wave grid
    const int l15 = lane & 15, g = lane >> 4;

    const int swzr = (l15 >> 1) & 7;
    const int pc0 = (g ^ swzr) * 8;          // ks0 elem offset; ks1 = pc0^32

    const int r8 = lane >> 3, c8 = lane & 7;
    const bf16* agp[4]; const bf16* bgp[2];
    int aldso[4], bldso[2];
#pragma unroll
    for (int j = 0; j < 4; ++j) {
        int br = w * 32 + j * 8 + r8;        // A row 0..255
        int swz = (br >> 1) & 7;
        agp[j] = A + (size_t)(bm + br) * K + (c8 ^ swz) * 8;
        aldso[j] = (w * 32 + j * 8) * 64;
    }
#pragma unroll
    for (int j = 0; j < 2; ++j) {
        int br = w * 16 + j * 8 + r8;        // B row 0..127
        int swz = (br >> 1) & 7;
        bgp[j] = Bt + (size_t)(bn + br) * K + (c8 ^ swz) * 8;
        bldso[j] = ABUF + (w * 16 + j * 8) * 64;
    }

    f32x4 acc[4][4];
#pragma unroll
    for (int m = 0; m < 4; ++m)
#pragma unroll
        for (int n = 0; n < 4; ++n) acc[m][n] = (f32x4){0.f, 0.f, 0.f, 0.f};

    {   // prologue: stage tile 0
#pragma unroll
        for (int j = 0; j < 4; ++j) gload16(agp[j], smem + aldso[j]);
#pragma unroll
        for (int j = 0; j < 2; ++j) gload16(bgp[j], smem + bldso[j]);
    }
    __syncthreads();
    int cur = 0;

    const int NT = K / 64;
    for (int t = 0; t < NT; ++t) {
        const bf16* Ar = smem + cur * BUFE;
        const bf16* Br = Ar + ABUF;
        bf16* nbase = smem + (cur ^ 1) * BUFE;
        const int k0n = (t + 1) * 64;
        const bool st = (t < NT - 1);
        if (st) {
#pragma unroll
            for (int j = 0; j < 4; ++j) gload16(agp[j] + k0n, nbase + aldso[j]);
        }
        bf16x8 af[4], bfv[4];
        // ---- ks = 0 ----
#pragma unroll
        for (int m = 0; m < 4; ++m)
            af[m] = *(const bf16x8*)&Ar[(wm * 64 + m * 16 + l15) * 64 + pc0];
#pragma unroll
        for (int n = 0; n < 4; ++n)
            bfv[n] = *(const bf16x8*)&Br[(wn * 64 + n * 16 + l15) * 64 + pc0];
        __builtin_amdgcn_s_setprio(1);
#pragma unroll
        for (int m = 0; m < 4; ++m)
#pragma unroll
            for (int n = 0; n < 4; ++n)
                acc[m][n] = __builtin_amdgcn_mfma_f32_16x16x32_bf16(af[m], bfv[n], acc[m][n], 0, 0, 0);
        __builtin_amdgcn_s_setprio(0);
        if (st) {
#pragma unroll
            for (int j = 0; j < 2; ++j) gload16(bgp[j] + k0n, nbase + bldso[j]);
        }
        // ---- ks = 1 ----
#pragma unroll
        for (int m = 0; m < 4; ++m)
            af[m] = *(const bf16x8*)&Ar[(wm * 64 + m * 16 + l15) * 64 + (pc0 ^ 32)];
#pragma unroll
        for (int n = 0; n < 4; ++n)
            bfv[n] = *(const bf16x8*)&Br[(wn * 64 + n * 16 + l15) * 64 + (pc0 ^ 32)];
        __builtin_amdgcn_s_setprio(1);
#pragma unroll
        for (int m = 0; m < 4; ++m)
#pragma unroll
            for (int n = 0; n < 4; ++n)
                acc[m][n] = __builtin_amdgcn_mfma_f32_16x16x32_bf16(af[m], bfv[n], acc[m][n], 0, 0, 0);
        __builtin_amdgcn_s_setprio(0);
        __syncthreads();            // drains vmcnt(0): next buffer published
        cur ^= 1;
    }

    const int lq = g * 4;
#pragma unroll
    for (int m = 0; m < 4; ++m) {
#pragma unroll
        for (int n = 0; n < 4; ++n) {
            int col = bn + wn * 64 + n * 16 + l15;
            float bv = bias[col];
            if (EPI == 4 && col >= 2 * DD) {
                int row0 = bm + wm * 64 + m * 16 + lq;
                int b = row0 >> 10, t0 = row0 & 1023;
                int hd = col - 2 * DD;
                union { bf16 h[4]; unsigned long long u; } pk;
#pragma unroll
                for (int j = 0; j < 4; ++j) pk.h[j] = (bf16)(acc[m][n][j] + bv);
                *(unsigned long long*)&vtout[((size_t)(b * DD + hd)) * TT + t0] = pk.u;
            } else {
#pragma unroll
                for (int j = 0; j < 4; ++j) {
                    int row = bm + wm * 64 + m * 16 + lq + j;
                    float v = acc[m][n][j] + bv;
                    if (EPI == 3) {
                        v = 0.5f * v * (1.f + erff(v * 0.70710678118654752f));
                        ((bf16*)Cout)[(size_t)row * N + col] = (bf16)v;
                    } else { // EPI == 4 Q/K columns
                        if (col < DD) v *= 0.125f;
                        ((bf16*)Cout)[(size_t)row * N + col] = (bf16)v;
                    }
                }
            }
        }
    }
}

// ---------------- LM head GEMM: 256x256 tile, 8 waves, BK=64 (r8 schedule) ----
__global__ __launch_bounds__(512, 2) void lmgemm(const bf16* __restrict__ A,
                                                 const bf16* __restrict__ Bt,
                                                 float* __restrict__ C) {
    constexpr int BUFE = 2 * 256 * 64;       // A+B elements per buffer
    __shared__ __align__(16) bf16 smem[2 * BUFE];   // 128 KiB
    const int orig = blockIdx.x;             // 0..1023
    const int xcd = orig & 7, local = orig >> 3;
    const int bnb = xcd * 16 + (local >> 3);
    if (bnb >= 125) return;
    const int bm = (local & 7) * 256;
    const int bn = bnb * 256;
    const int tid = threadIdx.x;
    const int w = tid >> 6, lane = tid & 63;
    const int wm = w >> 2, wn = w & 3;
    const int l15 = lane & 15, g = lane >> 4;

    const int swzr = (l15 >> 1) & 7;
    const int pc0 = (g ^ swzr) * 8;          // ks0 element offset; ks1 = pc0^32

    const int r8 = lane >> 3, c8 = lane & 7;
    const bf16* agp[4]; const bf16* bgp[4];
    int aldso[4], bldso[4];
#pragma unroll
    for (int j = 0; j < 4; ++j) {
        int br = w * 32 + j * 8 + r8;        // 0..255 within tile
        int swz = (br >> 1) & 7;
        agp[j] = A  + (size_t)(bm + br) * DD + (c8 ^ swz) * 8;
        bgp[j] = Bt + (size_t)(bn + br) * DD + (c8 ^ swz) * 8;
        aldso[j] = (w * 32 + j * 8) * 64;
        bldso[j] = 256 * 64 + (w * 32 + j * 8) * 64;
    }

    f32x4 acc[8][4];
#pragma unroll
    for (int m = 0; m < 8; ++m)
#pragma unroll
        for (int n = 0; n < 4; ++n) acc[m][n] = (f32x4){0.f, 0.f, 0.f, 0.f};

    {   // prologue: stage tile 0
        bf16* base = smem;
#pragma unroll
        for (int j = 0; j < 4; ++j) gload16(agp[j], base + aldso[j]);
#pragma unroll
        for (int j = 0; j < 4; ++j) gload16(bgp[j], base + bldso[j]);
    }
    __syncthreads();
    int cur = 0;

    for (int t = 0; t < 12; ++t) {
        const bf16* Ar = smem + cur * BUFE;
        const bf16* Br = Ar + 256 * 64;
        bf16* nbase = smem + (cur ^ 1) * BUFE;
        const int k0n = (t + 1) * 64;
        const bool st = (t < 11);
        if (st) {
#pragma unroll
            for (int j = 0; j < 4; ++j) gload16(agp[j] + k0n, nbase + aldso[j]);
        }
        bf16x8 af[8], bfv[4];
        // ---- ks = 0 ----
#pragma unroll
        for (int m = 0; m < 8; ++m)
            af[m] = *(const bf16x8*)&Ar[(wm * 128 + m * 16 + l15) * 64 + pc0];
#pragma unroll
        for (int n = 0; n < 4; ++n)
            bfv[n] = *(const bf16x8*)&Br[(wn * 64 + n * 16 + l15) * 64 + pc0];
        __builtin_amdgcn_s_setprio(1);
#pragma unroll
        for (int m = 0; m < 8; ++m)
#pragma unroll
            for (int n = 0; n < 4; ++n)
                acc[m][n] = __builtin_amdgcn_mfma_f32_16x16x32_bf16(af[m], bfv[n], acc[m][n], 0, 0, 0);
        __builtin_amdgcn_s_setprio(0);
        if (st) {
#pragma unroll
            for (int j = 0; j < 4; ++j) gload16(bgp[j] + k0n, nbase + bldso[j]);
        }
        // ---- ks = 1 ----
#pragma unroll
        for (int m = 0; m < 8; ++m)
            af[m] = *(const bf16x8*)&Ar[(wm * 128 + m * 16 + l15) * 64 + (pc0 ^ 32)];
#pragma unroll
        for (int n = 0; n < 4; ++n)
            bfv[n] = *(const bf16x8*)&Br[(wn * 64 + n * 16 + l15) * 64 + (pc0 ^ 32)];
        __builtin_amdgcn_s_setprio(1);
#pragma unroll
        for (int m = 0; m < 8; ++m)
#pragma unroll
            for (int n = 0; n < 4; ++n)
                acc[m][n] = __builtin_amdgcn_mfma_f32_16x16x32_bf16(af[m], bfv[n], acc[m][n], 0, 0, 0);
        __builtin_amdgcn_s_setprio(0);
        __syncthreads();            // drains vmcnt(0): next buffer published
        cur ^= 1;
    }

    // epilogue: per-wave disjoint LDS transpose, barrier-free, cached stores
    float* eb = (float*)smem + w * (16 * 68);
    const int rr = lane >> 2, c0 = (lane & 3) * 16;
#pragma unroll
    for (int mf = 0; mf < 8; ++mf) {
#pragma unroll
        for (int n = 0; n < 4; ++n)
#pragma unroll
            for (int j = 0; j < 4; ++j)
                eb[(g * 4 + j) * 68 + n * 16 + l15] = acc[mf][n][j];
        asm volatile("s_waitcnt lgkmcnt(0)" ::: "memory");   // writes visible in-wave
        const float* src = &eb[rr * 68 + c0];
        float* dst = C + (size_t)(bm + wm * 128 + mf * 16 + rr) * 32000 + bn + wn * 64 + c0;
        *(float4*)(dst + 0)  = *(const float4*)(src + 0);
        *(float4*)(dst + 4)  = *(const float4*)(src + 4);
        *(float4*)(dst + 8)  = *(const float4*)(src + 8);
        *(float4*)(dst + 12) = *(const float4*)(src + 12);
    }
}

// ---------------- MFMA flash attention (T14 async-stage: reg-preload next chunk) --
__global__ __launch_bounds__(256) void fattn_kernel(const bf16* __restrict__ qkv,
                                                    const bf16* __restrict__ vt,
                                                    bf16* __restrict__ o) {
    const int bh = blockIdx.y;
    const int b = bh / HH, h = bh % HH;
    const int qc = gridDim.x - 1 - blockIdx.x;   // longest blocks dispatch first
    const int q0 = qc * 64;
    const int tid = threadIdx.x;
    const int w = tid >> 6, lane = tid & 63;
    const int l15 = lane & 15, g = lane >> 4;

    __shared__ __align__(16) bf16 Ks[64 * 64];
    __shared__ __align__(16) bf16 Vs[64 * 64];
    __shared__ __align__(16) bf16 Ps[4][16 * 64];

    const size_t basebt = (size_t)b * TT;
    const int qw = q0 + w * 16;
    const int qg = qw + l15;

    bf16x8 bq0, bq1;
    {
        const bf16* qp = qkv + (basebt + qw + l15) * 2304 + h * 64 + g * 8;
        bq0 = *(const bf16x8*)(qp);
        bq1 = *(const bf16x8*)(qp + 32);
    }

    float mstate = -1e30f, lstate = 0.f;
    f32x4 oacc[4];
#pragma unroll
    for (int nf = 0; nf < 4; ++nf) oacc[nf] = (f32x4){0.f, 0.f, 0.f, 0.f};

    const int swzA = (l15 & 7) << 4;
    char* const psBase = (char*)&Ps[w][0];

    // staging coords + prologue: chunk 0 into regs
    const int r0 = tid >> 3;
    const int e0 = (tid & 7) * 8;
    bf16x8 kreg[2], vreg[2];
#pragma unroll
    for (int i = 0; i < 2; ++i) {
        int r = r0 + 32 * i;
        kreg[i] = *(const bf16x8*)&qkv[(basebt + r) * 2304 + DD + h * 64 + e0];
        vreg[i] = *(const bf16x8*)&vt[((size_t)bh * 64 + r) * TT + e0];
    }

    const int nchunk = qc + 1;
    for (int c = 0; c < nchunk; ++c) {
        const int kc = c * 64;
        // publish staged regs to LDS (previous readers finished at bottom barrier)
#pragma unroll
        for (int i = 0; i < 2; ++i) {
            int r = r0 + 32 * i;
            int swzW = (r & 7) << 4;
            *(bf16x8*)((char*)Ks + r * 128 + ((e0 * 2) ^ swzW)) = kreg[i];
            *(bf16x8*)((char*)Vs + r * 128 + ((e0 * 2) ^ swzW)) = vreg[i];
        }
        __syncthreads();
        // T14: issue next chunk's loads now; latency hides under compute below
        if (c + 1 < nchunk) {
            const int kc2 = kc + 64;
#pragma unroll
            for (int i = 0; i < 2; ++i) {
                int r = r0 + 32 * i;
                kreg[i] = *(const bf16x8*)&qkv[(basebt + kc2 + r) * 2304 + DD + h * 64 + e0];
                vreg[i] = *(const bf16x8*)&vt[((size_t)bh * 64 + r) * TT + kc2 + e0];
            }
        }
        if (kc <= qw + 15) {
            f32x4 s[4];
            __builtin_amdgcn_s_setprio(1);
#pragma unroll
            for (int mf = 0; mf < 4; ++mf) {
                char* kr = (char*)Ks + (16 * mf + l15) * 128;
                bf16x8 ka0 = *(const bf16x8*)(kr + ((16 * g) ^ swzA));
                bf16x8 ka1 = *(const bf16x8*)(kr + ((64 + 16 * g) ^ swzA));
                f32x4 a = (f32x4){0.f, 0.f, 0.f, 0.f};
                a = __builtin_amdgcn_mfma_f32_16x16x32_bf16(ka0, bq0, a, 0, 0, 0);
                a = __builtin_amdgcn_mfma_f32_16x16x32_bf16(ka1, bq1, a, 0, 0, 0);
                s[mf] = a;
            }
            __builtin_amdgcn_s_setprio(0);
            if (kc + 63 > qw) {
#pragma unroll
                for (int mf = 0; mf < 4; ++mf)
#pragma unroll
                    for (int j = 0; j < 4; ++j)
                        if (kc + 16 * mf + 4 * g + j > qg) s[mf][j] = -1e30f;
            }
            float cm = -1e30f;
#pragma unroll
            for (int mf = 0; mf < 4; ++mf)
#pragma unroll
                for (int j = 0; j < 4; ++j) cm = fmaxf(cm, s[mf][j]);
            cm = fmaxf(cm, __shfl_xor(cm, 16));
            cm = fmaxf(cm, __shfl_xor(cm, 32));
            float mnew = fmaxf(mstate, cm);
            float sc = __expf(mstate - mnew);
            mstate = mnew;
            float p[4][4];
            float psum = 0.f;
#pragma unroll
            for (int mf = 0; mf < 4; ++mf)
#pragma unroll
                for (int j = 0; j < 4; ++j) { float pv = __expf(s[mf][j] - mnew); p[mf][j] = pv; psum += pv; }
            psum += __shfl_xor(psum, 16);
            psum += __shfl_xor(psum, 32);
            lstate = lstate * sc + psum;
#pragma unroll
            for (int mf = 0; mf < 4; ++mf) {
                unsigned lo = pack_bf16x2(p[mf][0], p[mf][1]);
                unsigned hi = pack_bf16x2(p[mf][2], p[mf][3]);
                char* dst = psBase + l15 * 128 + ((32 * mf + 8 * g) ^ swzA);
                *(unsigned*)dst = lo;
                *(unsigned*)(dst + 4) = hi;
            }
            float s0 = __shfl(sc, 4 * g + 0), s1 = __shfl(sc, 4 * g + 1);
            float s2 = __shfl(sc, 4 * g + 2), s3 = __shfl(sc, 4 * g + 3);
#pragma unroll
            for (int nf = 0; nf < 4; ++nf) {
                oacc[nf][0] *= s0; oacc[nf][1] *= s1; oacc[nf][2] *= s2; oacc[nf][3] *= s3;
            }
            bf16x8 pa0 = *(const bf16x8*)(psBase + l15 * 128 + ((16 * g) ^ swzA));
            bf16x8 pa1 = *(const bf16x8*)(psBase + l15 * 128 + ((64 + 16 * g) ^ swzA));
            __builtin_amdgcn_s_setprio(1);
#pragma unroll
            for (int nf = 0; nf < 4; ++nf) {
                char* vr = (char*)Vs + (16 * nf + l15) * 128;
                bf16x8 vb0 = *(const bf16x8*)(vr + ((16 * g) ^ swzA));
                bf16x8 vb1 = *(const bf16x8*)(vr + ((64 + 16 * g) ^ swzA));
                oacc[nf] = __builtin_amdgcn_mfma_f32_16x16x32_bf16(pa0, vb0, oacc[nf], 0, 0, 0);
                oacc[nf] = __builtin_amdgcn_mfma_f32_16x16x32_bf16(pa1, vb1, oacc[nf], 0, 0, 0);
            }
            __builtin_amdgcn_s_setprio(0);
        }
        __syncthreads();   // all reads of LDS[c] done before next publish
    }
    float linv = 1.f / lstate;
    float l0 = __shfl(linv, 4 * g + 0), l1 = __shfl(linv, 4 * g + 1);
    float l2 = __shfl(linv, 4 * g + 2), l3 = __shfl(linv, 4 * g + 3);
    float lj[4] = {l0, l1, l2, l3};
#pragma unroll
    for (int j = 0; j < 4; ++j) {
        bf16* orow = o + (size_t)(basebt + qw + 4 * g + j) * DD + h * 64 + l15;
#pragma unroll
        for (int nf = 0; nf < 4; ++nf)
            orow[16 * nf] = (bf16)(oacc[nf][j] * lj[j]);
    }
}

// ---------------- launcher ----------------
extern "C" void kernel_launch(void* const* d_in, const int* in_sizes, int n_in,
                              void* d_out, int out_size, void* d_ws, size_t ws_size,
                              hipStream_t stream) {
    (void)in_sizes; (void)n_in; (void)out_size; (void)ws_size;
    const int*   idx  = (const int*)d_in[0];
    const float* tok  = (const float*)d_in[1];
    const float* pos  = (const float*)d_in[2];
    const float* Wqkv = (const float*)d_in[3];
    const float* bqkv = (const float*)d_in[4];
    const float* Wo   = (const float*)d_in[5];
    const float* bo   = (const float*)d_in[6];
    const float* ln1g = (const float*)d_in[7];
    const float* ln1b = (const float*)d_in[8];
    const float* ln2g = (const float*)d_in[9];
    const float* ln2b = (const float*)d_in[10];
    const float* W1   = (const float*)d_in[11];
    const float* b1   = (const float*)d_in[12];
    const float* W2   = (const float*)d_in[13];
    const float* b2   = (const float*)d_in[14];
    const float* lnfg = (const float*)d_in[15];
    const float* lnfb = (const float*)d_in[16];
    const float* Wlm  = (const float*)d_in[17];
    float* out = (float*)d_out;

    char* ws = (char*)d_ws;
    float* x     = (float*)(ws);                       // 6,291,456
    bf16*  abuf0 = (bf16*)(ws + 6291456);              // 3,145,728
    bf16*  abuf1 = (bf16*)(ws + 9437184);              // 12,582,912
    bf16*  qkvb  = (bf16*)(ws + 22020096);             // 9,437,184
    bf16*  vtb   = (bf16*)(ws + 31457280);             // 3,145,728
    bf16*  wbuf  = (bf16*)(ws + 34603008);             // 49,152,000

    bf16* wq = wbuf;              // 2304x768
    bf16* wo = wbuf + 1769472;    // 768x768
    bf16* w1 = wbuf + 2359296;    // 3072x768
    bf16* w2 = wbuf + 4718592;    // 768x3072

    embed_kernel<<<NTOK, 256, 0, stream>>>(idx, tok, pos, x);

    for (int l = 0; l < LLAY; ++l) {
        convT4_kernel<<<1728, 256, 0, stream>>>(
            Wqkv + (size_t)l * DD * 3 * DD, Wo + (size_t)l * DD * DD,
            W1 + (size_t)l * DD * DFFN, W2 + (size_t)l * DFFN * DD,
            wq, wo, w1, w2);
        ln_kernel<<<NTOK / 4, 256, 0, stream>>>(x, ln1g + l * DD, ln1b + l * DD, abuf0);
        bgemm<4><<<dim3(3 * DD / 128, NTOK / 256), 512, 0, stream>>>(
            abuf0, wq, bqkv + (size_t)l * 3 * DD, qkvb, vtb, 3 * DD, DD);
        fattn_kernel<<<dim3(TT / 64, BB * HH), 256, 0, stream>>>(qkvb, vtb, abuf0);
        mgemm<64, 2><<<dim3(DD / 128, NTOK / 64), 256, 0, stream>>>(
            abuf0, wo, bo + (size_t)l * DD, x, x, nullptr, NTOK, DD, DD);
        ln_kernel<<<NTOK / 4, 256, 0, stream>>>(x, ln2g + l * DD, ln2b + l * DD, abuf0);
        bgemm<3><<<dim3(DFFN / 128, NTOK / 256), 512, 0, stream>>>(
            abuf0, w1, b1 + (size_t)l * DFFN, abuf1, nullptr, DFFN, DD);
        mgemm<64, 2><<<dim3(DD / 128, NTOK / 64), 256, 0, stream>>>(
            abuf1, w2, b2 + (size_t)l * DD, x, x, nullptr, NTOK, DD, DFFN);
    }
    ln_kernel<<<NTOK / 4, 256, 0, stream>>>(x, lnfg, lnfb, abuf0);
    convT_kernel<<<dim3(32000 / 64, DD / 64), 256, 0, stream>>>(Wlm, wbuf, DD, 32000);
    lmgemm<<<1024, 512, 0, stream>>>(abuf0, wbuf, out);
}